// Round 10
// baseline (114.258 us; speedup 1.0000x reference)
//

#include <hip/hip_runtime.h>
#include <hip/hip_bf16.h>

#define NN 2048   // nodes
#define NW 64     // u32 words per bitmap row (2048 bits)

// ---------------- zero bitmaps (ws is poisoned 0xAA each call) --------------
__global__ void k_zero_r10(unsigned* __restrict__ p, int n) {
    int i = blockIdx.x * blockDim.x + threadIdx.x;
    int stride = gridDim.x * blockDim.x;
    for (; i < n; i += stride) p[i] = 0u;
}

// ---------------- build A and A^T as row bitmaps (dedups duplicate edges) ---
__global__ void k_build_r10(const int* __restrict__ ei, int E,
                            unsigned* __restrict__ Abits, unsigned* __restrict__ ATbits) {
    int e = blockIdx.x * blockDim.x + threadIdx.x;
    if (e >= E) return;
    int s = ei[e] & (NN - 1);        // edge_index[0] = source
    int d = ei[E + e] & (NN - 1);    // edge_index[1] = target
    atomicOr(&Abits[s * NW + (d >> 5)], 1u << (d & 31));
    atomicOr(&ATbits[d * NW + (s >> 5)], 1u << (s & 31));
}

// ---------------- per-row pan nnz -> dinv, bit-sliced, no LDS ---------------
// pan[i][j] = w0*(i==j) + w1*A[i][j] + w2*c(i,j), c = #paths i->k->j.
// Per lane: 32 columns; c kept in 7 carry-save bit-slices (0..127).
// nnz (j != i): (a | c>0) & ~(a & c == -w1/w2)   [exact for any weights]
__global__ void __launch_bounds__(256) k_pandeg_r10(
        const unsigned* __restrict__ Abits,
        const float* __restrict__ fw1, const float* __restrict__ fw2,
        float* __restrict__ dinv1, float* __restrict__ dinv2) {
    int tid = threadIdx.x, lane = tid & 63;
    int i = blockIdx.x * 4 + (tid >> 6);
    unsigned row = Abits[i * NW + lane];
    unsigned b0 = 0, b1 = 0, b2 = 0, b3 = 0, b4 = 0, b5 = 0, b6 = 0;
    for (int wi = 0; wi < NW; wi++) {
        unsigned wv = __shfl(row, wi);           // lockstep neighbor enumeration
        while (wv) {
            int bb = __ffs(wv) - 1; wv &= wv - 1;
            unsigned carry = Abits[(wi * 32 + bb) * NW + lane], t;
            t = b0 ^ carry; carry &= b0; b0 = t;
            t = b1 ^ carry; carry &= b1; b1 = t;
            t = b2 ^ carry; carry &= b2; b2 = t;
            t = b3 ^ carry; carry &= b3; b3 = t;
            t = b4 ^ carry; carry &= b4; b4 = t;
            t = b5 ^ carry; carry &= b5; b5 = t;
            b6 ^= carry;
        }
    }
    unsigned nz = b0 | b1 | b2 | b3 | b4 | b5 | b6;
    int dl = i >> 5, db = i & 31;
    unsigned ci = ((b0 >> db) & 1u) | (((b1 >> db) & 1u) << 1) | (((b2 >> db) & 1u) << 2)
                | (((b3 >> db) & 1u) << 3) | (((b4 >> db) & 1u) << 4)
                | (((b5 >> db) & 1u) << 5) | (((b6 >> db) & 1u) << 6);

    float ws[6] = { fw1[0], fw1[1], fw1[2], fw2[0], fw2[1], fw2[2] };
    int cnts[2];
#pragma unroll
    for (int setk = 0; setk < 2; setk++) {
        float w0 = ws[setk * 3], w1 = ws[setk * 3 + 1], w2 = ws[setk * 3 + 2];
        unsigned m;
        bool useA = (w1 != 0.f), useC = (w2 != 0.f);
        if (useA && useC) {
            m = row | nz;
            float c0f = -w1 / w2;                  // cancellation count, if integral
            int c0 = (int)rintf(c0f);
            if (c0 >= 1 && c0 <= 127 && fabsf(c0f - (float)c0) < 1e-5f) {
                unsigned eq = 0xFFFFFFFFu;
                eq &= (c0 & 1)  ? b0 : ~b0;
                eq &= (c0 & 2)  ? b1 : ~b1;
                eq &= (c0 & 4)  ? b2 : ~b2;
                eq &= (c0 & 8)  ? b3 : ~b3;
                eq &= (c0 & 16) ? b4 : ~b4;
                eq &= (c0 & 32) ? b5 : ~b5;
                eq &= (c0 & 64) ? b6 : ~b6;
                m &= ~(row & eq);
            }
        } else if (useA) m = row;
        else if (useC)   m = nz;
        else             m = 0u;
        int cnt;
        if (lane == dl) {                          // diagonal handled exactly
            unsigned a = (row >> db) & 1u;
            float pv = w0 + w1 * (float)a + w2 * (float)ci;
            cnt = __popc(m & ~(1u << db)) + (pv != 0.f ? 1 : 0);
        } else cnt = __popc(m);
        cnts[setk] = cnt;
    }
    int c1 = cnts[0], c2 = cnts[1];
    for (int o = 32; o; o >>= 1) { c1 += __shfl_down(c1, o); c2 += __shfl_down(c2, o); }
    if (lane == 0) {
        dinv1[i] = c1 > 0 ? rsqrtf((float)c1) : 0.f;
        dinv2[i] = c2 > 0 ? rsqrtf((float)c2) : 0.f;
    }
}

// ---------------- layer-1 linear: y[i][c] = dinv[i]*(x[i,:].W1[c,:] + b[c]) -
// Group-padded LDS (m = f + f/32): segs hit distinct banks, conflict-free.
__global__ void __launch_bounds__(256) k_lin1_r10(
        const float* __restrict__ x, const float* __restrict__ W,
        const float* __restrict__ b, const float* __restrict__ dinv,
        float* __restrict__ y) {
    __shared__ float xs[528];                    // 512 + 16 pad
    int i = blockIdx.x, tid = threadIdx.x;
    if (tid < 128) {                             // coalesced float4 stage
        float4 v = ((const float4*)(x + i * 512))[tid];
        int f = tid * 4;
        int m = f + (f >> 5);
        xs[m] = v.x; xs[m + 1] = v.y; xs[m + 2] = v.z; xs[m + 3] = v.w;
    }
    __syncthreads();
    int c = tid >> 4, seg = tid & 15;            // 16 channels x 16 segments
    const float* wr = W + c * 512 + seg * 32;    // contiguous -> b128 loads
    const float* xr = xs + seg * 33;
    float s = 0.f;
#pragma unroll
    for (int f = 0; f < 32; f++) s += xr[f] * wr[f];
    for (int o = 8; o; o >>= 1) s += __shfl_down(s, o, 16);
    if (seg == 0) y[i * 16 + c] = dinv[i] * (s + b[c]);
}

// ---------------- SpMM F=16: t[i][:] = sum_{j: A[j][i]=1} y1[j][:] ----------
__global__ void __launch_bounds__(256) k_spmm16_r10(
        const unsigned* __restrict__ ATbits, const float* __restrict__ y,
        float* __restrict__ t) {
    __shared__ int neigh[4][64];
    __shared__ int ncnt[4];
    int tid = threadIdx.x, w = tid >> 6, lane = tid & 63;
    int i = blockIdx.x * 4 + w;
    if (lane == 0) ncnt[w] = 0;
    __syncthreads();
    unsigned bits = ATbits[i * NW + lane];
    while (bits) {
        int b = __ffs(bits) - 1; bits &= bits - 1;
        int slot = atomicAdd(&ncnt[w], 1);
        if (slot < 64) neigh[w][slot] = lane * 32 + b;
    }
    __syncthreads();
    int nc = ncnt[w] < 64 ? ncnt[w] : 64;
    int c = lane & 15, grp = lane >> 4;
    float acc = 0.f;
    for (int n = grp; n < nc; n += 4) acc += y[neigh[w][n] * 16 + c];
    acc += __shfl_down(acc, 32);
    acc += __shfl_down(acc, 16);
    if (lane < 16) t[i * 16 + c] = acc;
}

// ---- layer-1 tail + FUSED layer-2 linear -----------------------------------
// h = relu(dinv1*(w0*y1 + w1*t1 + w2*(P t1)));  y2[i][c2] = dinv2*(h.W2[c2]+b2)
__global__ void __launch_bounds__(256) k_final1_lin2_r10(
        const unsigned* __restrict__ ATbits, const float* __restrict__ y,
        const float* __restrict__ t, const float* __restrict__ dinv1,
        const float* __restrict__ dinv2, const float* __restrict__ fw,
        const float* __restrict__ W2, const float* __restrict__ b2,
        float* __restrict__ y2) {
    __shared__ int neigh[4][64];
    __shared__ int ncnt[4];
    int tid = threadIdx.x, w = tid >> 6, lane = tid & 63;
    int i = blockIdx.x * 4 + w;
    if (lane == 0) ncnt[w] = 0;
    __syncthreads();
    unsigned bits = ATbits[i * NW + lane];
    while (bits) {
        int b = __ffs(bits) - 1; bits &= bits - 1;
        int slot = atomicAdd(&ncnt[w], 1);
        if (slot < 64) neigh[w][slot] = lane * 32 + b;
    }
    __syncthreads();
    int nc = ncnt[w] < 64 ? ncnt[w] : 64;
    int c = lane & 15, grp = lane >> 4;
    float acc = 0.f;
    for (int n = grp; n < nc; n += 4) acc += t[neigh[w][n] * 16 + c];
    acc += __shfl_down(acc, 32);
    acc += __shfl_down(acc, 16);
    float z = fw[0] * y[i * 16 + c] + fw[1] * t[i * 16 + c] + fw[2] * acc;
    z *= dinv1[i];
    z = z > 0.f ? z : 0.f;                       // h valid on lanes 0..15
    float s2 = 0.f;
#pragma unroll
    for (int f = 0; f < 16; f++) s2 += __shfl(z, f) * W2[lane * 16 + f];
    if (lane < 32) y2[i * 32 + lane] = dinv2[i] * (s2 + b2[lane]);
}

// ---------------- SpMM F=32: t2 = P y2 --------------------------------------
__global__ void __launch_bounds__(256) k_spmm32_r10(
        const unsigned* __restrict__ ATbits, const float* __restrict__ y,
        float* __restrict__ t) {
    __shared__ int neigh[4][64];
    __shared__ int ncnt[4];
    int tid = threadIdx.x, w = tid >> 6, lane = tid & 63;
    int i = blockIdx.x * 4 + w;
    if (lane == 0) ncnt[w] = 0;
    __syncthreads();
    unsigned bits = ATbits[i * NW + lane];
    while (bits) {
        int b = __ffs(bits) - 1; bits &= bits - 1;
        int slot = atomicAdd(&ncnt[w], 1);
        if (slot < 64) neigh[w][slot] = lane * 32 + b;
    }
    __syncthreads();
    int nc = ncnt[w] < 64 ? ncnt[w] : 64;
    int c = lane & 31, grp = lane >> 5;
    float acc = 0.f;
    for (int n = grp; n < nc; n += 2) acc += y[neigh[w][n] * 32 + c];
    acc += __shfl_down(acc, 32);
    if (lane < 32) t[i * 32 + c] = acc;
}

// ---------------- layer-2 tail + log_softmax -> fp32 ------------------------
__global__ void __launch_bounds__(256) k_final2_r10(
        const unsigned* __restrict__ ATbits, const float* __restrict__ y,
        const float* __restrict__ t, const float* __restrict__ dinv,
        const float* __restrict__ fw, float* __restrict__ out) {
    __shared__ int neigh[4][64];
    __shared__ int ncnt[4];
    int tid = threadIdx.x, w = tid >> 6, lane = tid & 63;
    int i = blockIdx.x * 4 + w;
    if (lane == 0) ncnt[w] = 0;
    __syncthreads();
    unsigned bits = ATbits[i * NW + lane];
    while (bits) {
        int b = __ffs(bits) - 1; bits &= bits - 1;
        int slot = atomicAdd(&ncnt[w], 1);
        if (slot < 64) neigh[w][slot] = lane * 32 + b;
    }
    __syncthreads();
    int nc = ncnt[w] < 64 ? ncnt[w] : 64;
    int c = lane & 31, grp = lane >> 5;
    float acc = 0.f;
    for (int n = grp; n < nc; n += 2) acc += t[neigh[w][n] * 32 + c];
    acc += __shfl_down(acc, 32);               // lanes 0..31 hold full sum
    float o = dinv[i] * (fw[0] * y[i * 32 + c] + fw[1] * t[i * 32 + c] + fw[2] * acc);
    float m = o;
    for (int k = 16; k; k >>= 1) m = fmaxf(m, __shfl_xor(m, k, 32));
    float e = expf(o - m);
    float ssum = e;
    for (int k = 16; k; k >>= 1) ssum += __shfl_xor(ssum, k, 32);
    if (lane < 32) out[i * 32 + c] = o - m - logf(ssum);
}

extern "C" void kernel_launch(void* const* d_in, const int* in_sizes, int n_in,
                              void* d_out, int out_size, void* d_ws, size_t ws_size,
                              hipStream_t stream) {
    const float* x   = (const float*)d_in[0];
    const int*   ei  = (const int*)d_in[1];
    const float* fw1 = (const float*)d_in[2];
    const float* W1  = (const float*)d_in[3];
    const float* b1  = (const float*)d_in[4];
    const float* fw2 = (const float*)d_in[5];
    const float* W2  = (const float*)d_in[6];
    const float* b2  = (const float*)d_in[7];
    float* out = (float*)d_out;                 // reference output dtype = float32
    int E = in_sizes[1] / 2;

    char* ws = (char*)d_ws;
    size_t off = 0;
    auto alloc = [&](size_t bytes) { void* p = ws + off; off += (bytes + 255) & ~size_t(255); return p; };
    unsigned* Abits  = (unsigned*)alloc(NN * NW * 4);
    unsigned* ATbits = (unsigned*)alloc(NN * NW * 4);
    float* dinv1 = (float*)alloc(NN * 4);
    float* dinv2 = (float*)alloc(NN * 4);
    float* y1 = (float*)alloc(NN * 16 * 4);
    float* t1 = (float*)alloc(NN * 16 * 4);
    float* y2 = (float*)alloc(NN * 32 * 4);
    float* t2 = (float*)alloc(NN * 32 * 4);
    (void)ws_size; (void)n_in; (void)out_size;

    k_zero_r10<<<256, 256, 0, stream>>>(Abits, 2 * NN * NW);  // Abits+ATbits contiguous
    k_build_r10<<<(E + 255) / 256, 256, 0, stream>>>(ei, E, Abits, ATbits);
    k_pandeg_r10<<<NN / 4, 256, 0, stream>>>(Abits, fw1, fw2, dinv1, dinv2);

    // layer 1 (+ fused layer-2 linear)
    k_lin1_r10<<<NN, 256, 0, stream>>>(x, W1, b1, dinv1, y1);
    k_spmm16_r10<<<NN / 4, 256, 0, stream>>>(ATbits, y1, t1);
    k_final1_lin2_r10<<<NN / 4, 256, 0, stream>>>(ATbits, y1, t1, dinv1, dinv2,
                                                  fw1, W2, b2, y2);
    // layer 2
    k_spmm32_r10<<<NN / 4, 256, 0, stream>>>(ATbits, y2, t2);
    k_final2_r10<<<NN / 4, 256, 0, stream>>>(ATbits, y2, t2, dinv2, fw2, out);
}